// Round 8
// baseline (1054.791 us; speedup 1.0000x reference)
//
#include <hip/hip_runtime.h>
#include <hip/hip_bf16.h>

#define NN 8192
#define KF 256
#define KD 512
#define CK 32
#define PACK 67108864.0   // 2^26 for (poscnt, negcnt) packing

typedef unsigned int uint32;
typedef unsigned short ushort16;
typedef __attribute__((ext_vector_type(8))) short bf16x8;
typedef __attribute__((ext_vector_type(4))) float f32x4;

static __device__ __forceinline__ float bf2f(ushort16 u) {
    union { uint32 i; float f; } v; v.i = ((uint32)u) << 16; return v.f;
}
static __device__ __forceinline__ ushort16 f2bf(float f) {
    __hip_bfloat16 h = __float2bfloat16(f);  // RNE
    union { __hip_bfloat16 h; ushort16 u; } v; v.h = h; return v.u;
}
// exact 3-way bf16 split: x = h + l + l2 + O(2^-26 x)
static __device__ __forceinline__ void split3(float x, ushort16& h, ushort16& l, ushort16& l2) {
    h = f2bf(x);
    float r1 = x - bf2f(h);
    l = f2bf(r1);
    float r2 = r1 - bf2f(l);
    l2 = f2bf(r2);
}

// ---------------- K0: detect input dtype (block 0) + zero accumulators ----------------
__global__ void detect_init_kernel(const uint32* __restrict__ rawA, int* __restrict__ flag,
                                   double* __restrict__ acc, double* __restrict__ gstats) {
    if (blockIdx.x == 0) {
        __shared__ int s_top2, s_nz;
        if (threadIdx.x == 0) { s_top2 = 0; s_nz = 0; }
        __syncthreads();
        int top2 = 0, nz = 0;
        for (int i = threadIdx.x; i < 4096; i += 256) {
            uint32 lo = rawA[i] & 0xFFFFu;
            if (lo & 0xC000u) top2 = 1;
            if (lo) nz = 1;
        }
        if (top2) atomicOr(&s_top2, 1);
        if (nz) atomicOr(&s_nz, 1);
        __syncthreads();
        if (threadIdx.x == 0) {
            int f;
            if (s_top2) f = 1;        // true fp32
            else if (s_nz) f = 0;     // bf16 storage
            else f = 1;               // fp32 holding bf16-rounded values
            *flag = f;
        }
    } else {
        int i = (blockIdx.x - 1) * 256 + threadIdx.x;
        if (i < 3 * NN) acc[i] = 0.0;
        if (i < 2) gstats[i] = 0.0;
    }
}

// ---------------- K1: top-32 mask + build split matrices Xh/Xl/Xl2 (bf16) + sq ----------------
__global__ void prep_kernel(const void* __restrict__ P_, const void* __restrict__ A_,
                            const int* __restrict__ flag,
                            ushort16* __restrict__ Xh, ushort16* __restrict__ Xl,
                            ushort16* __restrict__ Xl2, float* __restrict__ sq) {
    int f = *flag;
    int row = blockIdx.x * 4 + (threadIdx.x >> 6);
    int lane = threadIdx.x & 63;
    if (row >= NN) return;
    float a[4], p[4];
    bool sel[4] = {false, false, false, false};
    if (f) {
        const float* Ar = (const float*)A_ + (size_t)row * KF;
        const float* Pr = (const float*)P_ + (size_t)row * KF;
#pragma unroll
        for (int j = 0; j < 4; j++) {
            int k = lane + 64 * j;
            a[j] = Ar[k];
            p[j] = Pr[k];
        }
    } else {
        const __hip_bfloat16* Ar = (const __hip_bfloat16*)A_ + (size_t)row * KF;
        const __hip_bfloat16* Pr = (const __hip_bfloat16*)P_ + (size_t)row * KF;
#pragma unroll
        for (int j = 0; j < 4; j++) {
            int k = lane + 64 * j;
            a[j] = __bfloat162float(Ar[k]);
            p[j] = __bfloat162float(Pr[k]);
        }
    }
    for (int it = 0; it < CK; ++it) {
        float bv = -1.0f; int bi = KF;
#pragma unroll
        for (int j = 0; j < 4; j++) {
            int k = lane + 64 * j;
            if (!sel[j] && (a[j] > bv || (a[j] == bv && k < bi))) { bv = a[j]; bi = k; }
        }
        for (int off = 32; off > 0; off >>= 1) {
            float ov = __shfl_xor(bv, off);
            int   oi = __shfl_xor(bi, off);
            if (ov > bv || (ov == bv && oi < bi)) { bv = ov; bi = oi; }
        }
        if ((bi & 63) == lane) sel[bi >> 6] = true;
    }
    double sq_part = 0.0;
    size_t rb = (size_t)row * KD;
#pragma unroll
    for (int j = 0; j < 4; j++) {
        int k = lane + 64 * j;
        float c = 0.0f, s = 0.0f;
        if (sel[j]) {
            c = a[j] * cosf(p[j]);
            s = a[j] * sinf(p[j]);
            sq_part += (double)a[j] * (double)a[j];
        }
        ushort16 h, l, l2;
        split3(c, h, l, l2);
        Xh[rb + k] = h; Xl[rb + k] = l; Xl2[rb + k] = l2;
        split3(s, h, l, l2);
        Xh[rb + KF + k] = h; Xl[rb + KF + k] = l; Xl2[rb + KF + k] = l2;
    }
    for (int off = 32; off > 0; off >>= 1) sq_part += __shfl_xor(sq_part, off);
    if (lane == 0) sq[row] = (float)sq_part;
}

// ---------------- K2: symmetric bf16x3 MFMA GEMM, 128x128 tile, 256 thr ----------------
// LDS: 6 regions (Ah,Al,Al2,Bh,Bl,Bl2) x 128 rows x 32 bf16; slot (row,sp) holds
// data quad q = sp ^ ((row>>1)&3)  -> 2-way max on reads and writes.
#define MM(A, B)                                                                   \
    _Pragma("unroll") for (int tm = 0; tm < 4; tm++)                               \
    _Pragma("unroll") for (int tn = 0; tn < 4; tn++)                               \
        acc[tm][tn] = __builtin_amdgcn_mfma_f32_16x16x32_bf16(A[tm], B[tn], acc[tm][tn], 0, 0, 0);

#define LOADF(dst, region, wbase)                                                  \
    _Pragma("unroll") for (int t = 0; t < 4; t++)                                  \
        dst[t] = *(const bf16x8*)&lds4[(region)*512 + ((wbase) + t*16 + r15)*4 + qp];

#define GLOAD(gp, ldsidx)                                                          \
    __builtin_amdgcn_global_load_lds(                                              \
        (const __attribute__((address_space(1))) unsigned int*)(gp),               \
        (__attribute__((address_space(3))) unsigned int*)&lds4[ldsidx], 16, 0, 0)

__global__ __launch_bounds__(256)
void gemm_kernel(const ushort16* __restrict__ Xh, const ushort16* __restrict__ Xl,
                 const ushort16* __restrict__ Xl2, const float* __restrict__ sq,
                 void* __restrict__ outv, const int* __restrict__ flag,
                 double* __restrict__ rowsum, double* __restrict__ possum,
                 double* __restrict__ pcnt) {
    int bx = blockIdx.x, by = blockIdx.y;
    if (bx < by) return;                    // upper-triangle tiles only
    __shared__ uint4 lds4[3072];            // 48 KB
    int f = *flag;
    int tid = threadIdx.x;
    int w = tid >> 6;                       // wave 0..3
    int wm = w >> 1, wn = w & 1;            // 2x2 wave grid of 64x64 blocks
    int L = tid & 63, quad = L >> 4, r15 = L & 15;
    int qp = quad ^ ((r15 >> 1) & 3);       // frag-read swizzled quad slot
    int row0 = by * 128, col0 = bx * 128;

    f32x4 acc[4][4];
#pragma unroll
    for (int tm = 0; tm < 4; tm++)
#pragma unroll
        for (int tn = 0; tn < 4; tn++) acc[tm][tn] = (f32x4){0.f, 0.f, 0.f, 0.f};

    // per-lane global pointers for the 12 DMA instructions this wave issues
    // (j in {0,1} slot-chunks x 6 regions); slot s = w*128 + j*64 + L
    const ushort16* gp[12];
#pragma unroll
    for (int j = 0; j < 2; j++) {
        int s = w * 128 + j * 64 + L;
        int rr_ = s >> 2;
        int qq = (s & 3) ^ ((rr_ >> 1) & 3);
        size_t aoff = (size_t)(row0 + rr_) * KD + qq * 8;
        size_t boff = (size_t)(col0 + rr_) * KD + qq * 8;
        gp[j * 6 + 0] = Xh + aoff;  gp[j * 6 + 1] = Xl + aoff;  gp[j * 6 + 2] = Xl2 + aoff;
        gp[j * 6 + 3] = Xh + boff;  gp[j * 6 + 4] = Xl + boff;  gp[j * 6 + 5] = Xl2 + boff;
    }

    for (int t = 0; t < 16; t++) {
        const int ko = t * 32;
        __syncthreads();                    // all waves done reading previous tile
#pragma unroll
        for (int j = 0; j < 2; j++) {
            int lb = w * 128 + j * 64;
            GLOAD(gp[j * 6 + 0] + ko, 0 * 512 + lb);
            GLOAD(gp[j * 6 + 1] + ko, 1 * 512 + lb);
            GLOAD(gp[j * 6 + 2] + ko, 2 * 512 + lb);
            GLOAD(gp[j * 6 + 3] + ko, 3 * 512 + lb);
            GLOAD(gp[j * 6 + 4] + ko, 4 * 512 + lb);
            GLOAD(gp[j * 6 + 5] + ko, 5 * 512 + lb);
        }
        __syncthreads();                    // vmcnt drain -> tile resident

        bf16x8 fa[4], fb[4], ga[4], gb[4];
        LOADF(fa, 0, wm * 64)      // Ah
        LOADF(fb, 3, wn * 64)      // Bh
        MM(fa, fb)                 // h*h
        LOADF(gb, 4, wn * 64)      // Bl
        MM(fa, gb)                 // h*l
        LOADF(ga, 1, wm * 64)      // Al
        MM(ga, fb)                 // l*h
        MM(ga, gb)                 // l*l
        LOADF(gb, 5, wn * 64)      // Bl2 (overwrite)
        MM(fa, gb)                 // h*l2
        LOADF(ga, 2, wm * 64)      // Al2 (overwrite)
        MM(ga, fb)                 // l2*h
    }

    // ---- epilogue: R = num/denom in registers (C-layout: row=quad*4+g, col=r15) ----
    float sqj[4], sqiv[4][4];
#pragma unroll
    for (int tn = 0; tn < 4; tn++) sqj[tn] = sq[col0 + wn * 64 + tn * 16 + r15];
#pragma unroll
    for (int tm = 0; tm < 4; tm++)
#pragma unroll
        for (int g = 0; g < 4; g++) sqiv[tm][g] = sq[row0 + wm * 64 + tm * 16 + quad * 4 + g];
#pragma unroll
    for (int tm = 0; tm < 4; tm++)
#pragma unroll
        for (int tn = 0; tn < 4; tn++)
#pragma unroll
            for (int g = 0; g < 4; g++) {
                float denom = sqrtf(sqiv[tm][g] * sqj[tn] + 1e-10f);
                acc[tm][tn][g] = acc[tm][tn][g] / denom;   // IEEE div, matches np
            }

    // ---- row stats (direct tile) ----
#pragma unroll
    for (int tm = 0; tm < 4; tm++)
#pragma unroll
        for (int g = 0; g < 4; g++) {
            double rs_ = 0.0, ps_ = 0.0;
            float pc_ = 0.0f, nc_ = 0.0f;
#pragma unroll
            for (int tn = 0; tn < 4; tn++) {
                float r = acc[tm][tn][g];
                rs_ += (double)r;
                if (r > 0.0f) { ps_ += (double)r; pc_ += 1.0f; }
                else if (r < 0.0f) { nc_ += 1.0f; }
            }
            for (int off = 1; off < 16; off <<= 1) {
                rs_ += __shfl_xor(rs_, off);
                ps_ += __shfl_xor(ps_, off);
                pc_ += __shfl_xor(pc_, off);
                nc_ += __shfl_xor(nc_, off);
            }
            if (r15 == 0) {
                int gr = row0 + wm * 64 + tm * 16 + quad * 4 + g;
                atomicAdd(&rowsum[gr], rs_);
                atomicAdd(&possum[gr], ps_);
                atomicAdd(&pcnt[gr], (double)pc_ * PACK + (double)nc_);
            }
        }

    // ---- column stats (off-diagonal only) ----
    if (bx != by) {
#pragma unroll
        for (int tn = 0; tn < 4; tn++) {
            double cs = 0.0, cp = 0.0;
            float cc = 0.0f, cn = 0.0f;
#pragma unroll
            for (int tm = 0; tm < 4; tm++)
#pragma unroll
                for (int g = 0; g < 4; g++) {
                    float r = acc[tm][tn][g];
                    cs += (double)r;
                    if (r > 0.0f) { cp += (double)r; cc += 1.0f; }
                    else if (r < 0.0f) { cn += 1.0f; }
                }
            cs += __shfl_xor(cs, 16); cs += __shfl_xor(cs, 32);
            cp += __shfl_xor(cp, 16); cp += __shfl_xor(cp, 32);
            cc += __shfl_xor(cc, 16); cc += __shfl_xor(cc, 32);
            cn += __shfl_xor(cn, 16); cn += __shfl_xor(cn, 32);
            if (L < 16) {
                int gc = col0 + wn * 64 + tn * 16 + L;
                atomicAdd(&rowsum[gc], cs);
                atomicAdd(&possum[gc], cp);
                atomicAdd(&pcnt[gc], (double)cc * PACK + (double)cn);
            }
        }
    }

    // ---- stores via per-wave LDS transpose (16-row stripes) ----
    __syncthreads();                        // k-loop frag reads fully done
    float* W = (float*)(lds4 + w * 256);    // private 4 KB per wave: 16 x 64 fp32
    int rr = L >> 2, cc2 = L & 3;
#pragma unroll
    for (int tm = 0; tm < 4; tm++) {
#pragma unroll
        for (int tn = 0; tn < 4; tn++)
#pragma unroll
            for (int g = 0; g < 4; g++) {
                int nibS = tn * 4 + (((r15 >> 2) ^ g) & 3);
                W[(quad * 4 + g) * 64 + nibS * 4 + (r15 & 3)] = acc[tm][tn][g];
            }
        // direct store: thread -> 16 consecutive cols of row rr
        float vals[16];
#pragma unroll
        for (int j = 0; j < 4; j++) {
            int nibS = cc2 * 4 + ((j ^ (rr & 3)) & 3);
            float4 fv = *(const float4*)&W[rr * 64 + nibS * 4];
            vals[j * 4 + 0] = fv.x; vals[j * 4 + 1] = fv.y;
            vals[j * 4 + 2] = fv.z; vals[j * 4 + 3] = fv.w;
        }
        int gr = row0 + wm * 64 + tm * 16 + rr;
        size_t ob = ((size_t)gr << 13) + col0 + wn * 64 + cc2 * 16;
        if (f) {
            float* O = (float*)outv;
#pragma unroll
            for (int j = 0; j < 4; j++)
                *(float4*)(O + ob + j * 4) =
                    make_float4(vals[j * 4], vals[j * 4 + 1], vals[j * 4 + 2], vals[j * 4 + 3]);
        } else {
            union { uint4 u; ushort16 s[8]; } p0, p1;
#pragma unroll
            for (int j = 0; j < 8; j++) p0.s[j] = f2bf(vals[j]);
#pragma unroll
            for (int j = 0; j < 8; j++) p1.s[j] = f2bf(vals[8 + j]);
            *(uint4*)((__hip_bfloat16*)outv + ob) = p0.u;
            *(uint4*)((__hip_bfloat16*)outv + ob + 8) = p1.u;
        }
        // mirror store (off-diagonal): thread c=L -> 16 stripe-rows of col c, 32B contiguous
        if (bx != by) {
            float vm[16];
#pragma unroll
            for (int rw = 0; rw < 16; rw++) {
                int nibS = (L >> 4) * 4 + ((((L & 15) >> 2) ^ (rw & 3)) & 3);
                vm[rw] = W[rw * 64 + nibS * 4 + (L & 3)];
            }
            size_t obm = (((size_t)(col0 + wn * 64 + L)) << 13) + row0 + wm * 64 + tm * 16;
            if (f) {
                float* O = (float*)outv;
#pragma unroll
                for (int j = 0; j < 4; j++)
                    *(float4*)(O + obm + j * 4) =
                        make_float4(vm[j * 4], vm[j * 4 + 1], vm[j * 4 + 2], vm[j * 4 + 3]);
            } else {
                union { uint4 u; ushort16 s[8]; } m0, m1;
#pragma unroll
                for (int j = 0; j < 8; j++) m0.s[j] = f2bf(vm[j]);
#pragma unroll
                for (int j = 0; j < 8; j++) m1.s[j] = f2bf(vm[8 + j]);
                *(uint4*)((__hip_bfloat16*)outv + obm) = m0.u;
                *(uint4*)((__hip_bfloat16*)outv + obm + 8) = m1.u;
            }
        }
        __syncthreads();   // stripe fence (uniform across waves)
    }
}

// ---------------- K3: per-row finalize + global positive stats ----------------
__global__ void rowfin_kernel(const double* __restrict__ rowsum, const double* __restrict__ possum,
                              const double* __restrict__ pcnt,
                              float* __restrict__ inv_rs, double* __restrict__ gstats) {
    __shared__ double sc[256], sn[256];
    int n = blockIdx.x * 256 + threadIdx.x;
    double rsumv = rowsum[n];
    double rs = rsumv + 1e-10;
    inv_rs[n] = (float)(1.0 / rs);
    double packed = pcnt[n];
    double pc = floor(packed * (1.0 / PACK));
    double nc = packed - pc * PACK;
    double contrib, cnt;
    if (rs > 0.0) { contrib = possum[n] / rs; cnt = pc; }
    else          { contrib = (rsumv - possum[n]) / rs; cnt = nc; }
    sc[threadIdx.x] = contrib; sn[threadIdx.x] = cnt;
    __syncthreads();
    for (int s = 128; s > 0; s >>= 1) {
        if (threadIdx.x < s) { sc[threadIdx.x] += sc[threadIdx.x + s]; sn[threadIdx.x] += sn[threadIdx.x + s]; }
        __syncthreads();
    }
    if (threadIdx.x == 0) { atomicAdd(&gstats[0], sc[0]); atomicAdd(&gstats[1], sn[0]); }
}

// ---------------- K3b: tau ----------------
__global__ void tau_kernel(const double* __restrict__ gstats, float* __restrict__ tau) {
    double cnt = gstats[1];
    if (cnt < 1.0) cnt = 1.0;
    double mp = gstats[0] / cnt;
    tau[0] = (mp > 0.0) ? (float)mp : 1.0f;   // TAU_FACTOR = 1.0
}

// ---------------- K4: R' = R*inv_rs, threshold, in-place on d_out ----------------
__global__ void thresh_kernel(void* __restrict__ R_,
                              const float* __restrict__ inv_rs,
                              const float* __restrict__ tau_p,
                              const int* __restrict__ flag) {
    int f = *flag;
    float tau = *tau_p;
    size_t base = ((size_t)blockIdx.x * 256 + threadIdx.x) * 8;
    if (base >= (size_t)NN * NN) return;
    float inv = inv_rs[base >> 13];
    if (f) {
        float* R = (float*)R_;
        float4 v0 = *(float4*)(R + base);
        float4 v1 = *(float4*)(R + base + 4);
        float vv[8] = {v0.x, v0.y, v0.z, v0.w, v1.x, v1.y, v1.z, v1.w};
#pragma unroll
        for (int t = 0; t < 8; t++) {
            float val = vv[t] * inv;
            vv[t] = (val >= tau) ? val : 0.0f;
        }
        *(float4*)(R + base)     = make_float4(vv[0], vv[1], vv[2], vv[3]);
        *(float4*)(R + base + 4) = make_float4(vv[4], vv[5], vv[6], vv[7]);
    } else {
        __hip_bfloat16* R = (__hip_bfloat16*)R_;
        union { uint4 u; ushort16 s[8]; } in, out;
        in.u = *(const uint4*)(R + base);
#pragma unroll
        for (int t = 0; t < 8; t++) {
            float val = bf2f(in.s[t]) * inv;
            float r = (val >= tau) ? val : 0.0f;
            out.s[t] = f2bf(r);
        }
        *(uint4*)(R + base) = out.u;
    }
}

// ---------------- sentinel: ws too small -> unmistakable absmax signature ----------------
__global__ void sentinel_kernel(uint32* __restrict__ out, size_t n32) {
    size_t i = (size_t)blockIdx.x * 256 + threadIdx.x;
    if (i < n32) out[i] = 0x47C35000u;
}

extern "C" void kernel_launch(void* const* d_in, const int* in_sizes, int n_in,
                              void* d_out, int out_size, void* d_ws, size_t ws_size,
                              hipStream_t stream) {
    const void* P = d_in[0];
    const void* A = d_in[1];

    char* ws = (char*)d_ws;
    size_t off = 0;
    ushort16* Xh = (ushort16*)(ws + off);   off += (size_t)NN * KD * 2;   // 8 MB
    ushort16* Xl = (ushort16*)(ws + off);   off += (size_t)NN * KD * 2;   // 8 MB
    ushort16* Xl2 = (ushort16*)(ws + off);  off += (size_t)NN * KD * 2;   // 8 MB
    float* sqv = (float*)(ws + off);        off += (size_t)NN * 4;
    double* rowsum = (double*)(ws + off);   off += (size_t)NN * 8;
    double* possum = (double*)(ws + off);   off += (size_t)NN * 8;
    double* pcnt = (double*)(ws + off);     off += (size_t)NN * 8;
    float* inv_rs = (float*)(ws + off);     off += (size_t)NN * 4;
    double* gstats = (double*)(ws + off);   off += 16;
    float* tau = (float*)(ws + off);        off += 16;
    int* flag = (int*)(ws + off);           off += 16;

    if (ws_size < off) {
        size_t n32 = ((size_t)out_size * 2) / 4;
        sentinel_kernel<<<(int)((n32 + 255) / 256), 256, 0, stream>>>((uint32*)d_out, n32);
        return;
    }

    detect_init_kernel<<<1 + (3 * NN + 255) / 256, 256, 0, stream>>>((const uint32*)A, flag, rowsum, gstats);
    prep_kernel<<<NN / 4, 256, 0, stream>>>(P, A, flag, Xh, Xl, Xl2, sqv);
    dim3 ggrid(64, 64);
    gemm_kernel<<<ggrid, 256, 0, stream>>>(Xh, Xl, Xl2, sqv, d_out, flag, rowsum, possum, pcnt);
    rowfin_kernel<<<NN / 256, 256, 0, stream>>>(rowsum, possum, pcnt, inv_rs, gstats);
    tau_kernel<<<1, 1, 0, stream>>>(gstats, tau);
    thresh_kernel<<<(int)(((size_t)NN * NN / 8 + 255) / 256), 256, 0, stream>>>(d_out, inv_rs, tau, flag);
}

// Round 9
// 680.554 us; speedup vs baseline: 1.5499x; 1.5499x over previous
//
#include <hip/hip_runtime.h>
#include <hip/hip_bf16.h>

#define NN 8192
#define KF 256
#define KD 512
#define CK 32
#define PACK 67108864.0   // 2^26 for (poscnt, negcnt) packing

typedef unsigned int uint32;
typedef unsigned short ushort16;
typedef __attribute__((ext_vector_type(8))) short bf16x8;
typedef __attribute__((ext_vector_type(4))) float f32x4;

static __device__ __forceinline__ float bf2f(ushort16 u) {
    union { uint32 i; float f; } v; v.i = ((uint32)u) << 16; return v.f;
}
static __device__ __forceinline__ ushort16 f2bf(float f) {
    __hip_bfloat16 h = __float2bfloat16(f);  // RNE
    union { __hip_bfloat16 h; ushort16 u; } v; v.h = h; return v.u;
}
// exact 3-way bf16 split: x = h + l + l2 + O(2^-26 x)
static __device__ __forceinline__ void split3(float x, ushort16& h, ushort16& l, ushort16& l2) {
    h = f2bf(x);
    float r1 = x - bf2f(h);
    l = f2bf(r1);
    float r2 = r1 - bf2f(l);
    l2 = f2bf(r2);
}

// ---------------- K0: detect input dtype (block 0) + zero accumulators ----------------
__global__ void detect_init_kernel(const uint32* __restrict__ rawA, int* __restrict__ flag,
                                   double* __restrict__ acc, double* __restrict__ gstats) {
    if (blockIdx.x == 0) {
        __shared__ int s_top2, s_nz;
        if (threadIdx.x == 0) { s_top2 = 0; s_nz = 0; }
        __syncthreads();
        int top2 = 0, nz = 0;
        for (int i = threadIdx.x; i < 4096; i += 256) {
            uint32 lo = rawA[i] & 0xFFFFu;
            if (lo & 0xC000u) top2 = 1;
            if (lo) nz = 1;
        }
        if (top2) atomicOr(&s_top2, 1);
        if (nz) atomicOr(&s_nz, 1);
        __syncthreads();
        if (threadIdx.x == 0) {
            int f;
            if (s_top2) f = 1;        // true fp32
            else if (s_nz) f = 0;     // bf16 storage
            else f = 1;               // fp32 holding bf16-rounded values
            *flag = f;
        }
    } else {
        int i = (blockIdx.x - 1) * 256 + threadIdx.x;
        if (i < 3 * NN) acc[i] = 0.0;
        if (i < 2) gstats[i] = 0.0;
    }
}

// ---------------- K1: top-32 mask + build split matrices Xh/Xl/Xl2 (bf16) + sq ----------------
__global__ void prep_kernel(const void* __restrict__ P_, const void* __restrict__ A_,
                            const int* __restrict__ flag,
                            ushort16* __restrict__ Xh, ushort16* __restrict__ Xl,
                            ushort16* __restrict__ Xl2, float* __restrict__ sq) {
    int f = *flag;
    int row = blockIdx.x * 4 + (threadIdx.x >> 6);
    int lane = threadIdx.x & 63;
    if (row >= NN) return;
    float a[4], p[4];
    bool sel[4] = {false, false, false, false};
    if (f) {
        const float* Ar = (const float*)A_ + (size_t)row * KF;
        const float* Pr = (const float*)P_ + (size_t)row * KF;
#pragma unroll
        for (int j = 0; j < 4; j++) {
            int k = lane + 64 * j;
            a[j] = Ar[k];
            p[j] = Pr[k];
        }
    } else {
        const __hip_bfloat16* Ar = (const __hip_bfloat16*)A_ + (size_t)row * KF;
        const __hip_bfloat16* Pr = (const __hip_bfloat16*)P_ + (size_t)row * KF;
#pragma unroll
        for (int j = 0; j < 4; j++) {
            int k = lane + 64 * j;
            a[j] = __bfloat162float(Ar[k]);
            p[j] = __bfloat162float(Pr[k]);
        }
    }
    for (int it = 0; it < CK; ++it) {
        float bv = -1.0f; int bi = KF;
#pragma unroll
        for (int j = 0; j < 4; j++) {
            int k = lane + 64 * j;
            if (!sel[j] && (a[j] > bv || (a[j] == bv && k < bi))) { bv = a[j]; bi = k; }
        }
        for (int off = 32; off > 0; off >>= 1) {
            float ov = __shfl_xor(bv, off);
            int   oi = __shfl_xor(bi, off);
            if (ov > bv || (ov == bv && oi < bi)) { bv = ov; bi = oi; }
        }
        if ((bi & 63) == lane) sel[bi >> 6] = true;
    }
    double sq_part = 0.0;
    size_t rb = (size_t)row * KD;
#pragma unroll
    for (int j = 0; j < 4; j++) {
        int k = lane + 64 * j;
        float c = 0.0f, s = 0.0f;
        if (sel[j]) {
            c = a[j] * cosf(p[j]);
            s = a[j] * sinf(p[j]);
            sq_part += (double)a[j] * (double)a[j];
        }
        ushort16 h, l, l2;
        split3(c, h, l, l2);
        Xh[rb + k] = h; Xl[rb + k] = l; Xl2[rb + k] = l2;
        split3(s, h, l, l2);
        Xh[rb + KF + k] = h; Xl[rb + KF + k] = l; Xl2[rb + KF + k] = l2;
    }
    for (int off = 32; off > 0; off >>= 1) sq_part += __shfl_xor(sq_part, off);
    if (lane == 0) sq[row] = (float)sq_part;
}

// ---------------- K2: symmetric bf16x3 MFMA GEMM, 64x64 tile, dbuf DMA, 256 thr ----------------
// Per buffer: 6 regions (Ah,Al,Al2,Bh,Bl,Bl2) x 64 rows x 32 bf16 = 24 KB; dbuf = 48 KB.
// Region slot (row, sp) holds data-quad q = sp ^ ((row>>1)&3): 2-way max (R8-proven scheme).
#define MM2(A, B)                                                                  \
    _Pragma("unroll") for (int tm = 0; tm < 2; tm++)                               \
    _Pragma("unroll") for (int tn = 0; tn < 2; tn++)                               \
        acc[tm][tn] = __builtin_amdgcn_mfma_f32_16x16x32_bf16(A[tm], B[tn], acc[tm][tn], 0, 0, 0);

#define LOADF2(dst, p, rg, half)                                                   \
    _Pragma("unroll") for (int t = 0; t < 2; t++)                                  \
        dst[t] = *(const bf16x8*)&lds4[(p) * 1536 + (rg) * 256 + ((half) * 32 + t * 16 + r15) * 4 + qp];

#define GLOAD(gp, ldsidx)                                                          \
    __builtin_amdgcn_global_load_lds(                                              \
        (const __attribute__((address_space(1))) unsigned int*)(gp),               \
        (__attribute__((address_space(3))) unsigned int*)&lds4[ldsidx], 16, 0, 0)

#define GLOADALL(p, ko)                                                            \
    _Pragma("unroll") for (int j = 0; j < 6; j++)                                  \
        GLOAD(gptr[j] + (ko), (p) * 1536 + j * 256 + w * 64);

#define COMPUTE(p) {                                                               \
    bf16x8 fa[2], fb[2], ga[2], gb[2];                                             \
    LOADF2(fa, p, 0, wm)   /* Ah  */                                               \
    LOADF2(fb, p, 3, wn)   /* Bh  */                                               \
    MM2(fa, fb)            /* h*h */                                               \
    LOADF2(gb, p, 4, wn)   /* Bl  */                                               \
    MM2(fa, gb)            /* h*l */                                               \
    LOADF2(ga, p, 1, wm)   /* Al  */                                               \
    MM2(ga, fb)            /* l*h */                                               \
    MM2(ga, gb)            /* l*l */                                               \
    LOADF2(gb, p, 5, wn)   /* Bl2 */                                               \
    MM2(fa, gb)            /* h*l2 */                                              \
    LOADF2(ga, p, 2, wm)   /* Al2 */                                               \
    MM2(ga, fb)            /* l2*h */ }

__global__ __launch_bounds__(256)
void gemm_kernel(const ushort16* __restrict__ Xh, const ushort16* __restrict__ Xl,
                 const ushort16* __restrict__ Xl2, const float* __restrict__ sq,
                 void* __restrict__ outv, const int* __restrict__ flag,
                 double* __restrict__ rowsum, double* __restrict__ possum,
                 double* __restrict__ pcnt) {
    int bx = blockIdx.x, by = blockIdx.y;
    if (bx < by) return;                    // upper-triangle tiles only
    __shared__ uint4 lds4[3072];            // 48 KB = 2 x 1536 slots
    int f = *flag;
    int tid = threadIdx.x;
    int w = tid >> 6;                       // wave 0..3
    int wm = w >> 1, wn = w & 1;            // 2x2 wave grid of 32x32 blocks
    int L = tid & 63, quad = L >> 4, r15 = L & 15;
    int qp = quad ^ ((r15 >> 1) & 3);       // frag-read swizzled quad slot
    int row0 = by * 64, col0 = bx * 64;

    f32x4 acc[2][2];
#pragma unroll
    for (int tm = 0; tm < 2; tm++)
#pragma unroll
        for (int tn = 0; tn < 2; tn++) acc[tm][tn] = (f32x4){0.f, 0.f, 0.f, 0.f};

    // per-lane global pointers, one DMA per region per thread (slot-in-region = tid)
    const ushort16* gptr[6];
    {
        int row = tid >> 2, sp = tid & 3;
        int q = sp ^ ((row >> 1) & 3);
        const ushort16* srcs[6] = {Xh, Xl, Xl2, Xh, Xl, Xl2};
#pragma unroll
        for (int j = 0; j < 6; j++) {
            int tb = (j < 3) ? row0 : col0;
            gptr[j] = srcs[j] + (size_t)(tb + row) * KD + q * 8;
        }
    }

    // dbuf K-loop: ONE barrier per iter; tile t+1's DMAs issued right after the
    // barrier that opens tile t, so the next barrier's vmcnt(0) drain finds them done.
    GLOADALL(0, 0)
    for (int t = 0; t < 16; t += 2) {
        __syncthreads();
        if (t + 1 < 16) { GLOADALL(1, (t + 1) * 32) }
        COMPUTE(0)
        __syncthreads();
        if (t + 2 < 16) { GLOADALL(0, (t + 2) * 32) }
        COMPUTE(1)
    }

    // ---- R = num/denom in registers (C-layout: row=quad*4+g, col=r15) ----
    float sqj2[2], sqi2[2][4];
#pragma unroll
    for (int tn = 0; tn < 2; tn++) sqj2[tn] = sq[col0 + wn * 32 + tn * 16 + r15];
#pragma unroll
    for (int tm = 0; tm < 2; tm++)
#pragma unroll
        for (int g = 0; g < 4; g++) sqi2[tm][g] = sq[row0 + wm * 32 + tm * 16 + quad * 4 + g];
#pragma unroll
    for (int tm = 0; tm < 2; tm++)
#pragma unroll
        for (int tn = 0; tn < 2; tn++)
#pragma unroll
            for (int g = 0; g < 4; g++) {
                float denom = sqrtf(sqi2[tm][g] * sqj2[tn] + 1e-10f);
                acc[tm][tn][g] = acc[tm][tn][g] / denom;   // IEEE div, matches np
            }

    // ---- tile -> LDS (64 x 68 fp32), then coalesced stores + stats ----
    __syncthreads();                        // all frag ds_reads done; reuse lds4
    float* Wf = (float*)lds4;
#pragma unroll
    for (int tm = 0; tm < 2; tm++)
#pragma unroll
        for (int tn = 0; tn < 2; tn++)
#pragma unroll
            for (int g = 0; g < 4; g++)
                Wf[(wm * 32 + tm * 16 + quad * 4 + g) * 68 + wn * 32 + tn * 16 + r15] = acc[tm][tn][g];
    __syncthreads();

    int r = tid >> 2, cseg = tid & 3;       // row r, col segment cseg*16..+16
    float vals[16];
#pragma unroll
    for (int i4 = 0; i4 < 4; i4++) {
        float4 fv = *(const float4*)&Wf[r * 68 + cseg * 16 + i4 * 4];
        vals[i4 * 4 + 0] = fv.x; vals[i4 * 4 + 1] = fv.y;
        vals[i4 * 4 + 2] = fv.z; vals[i4 * 4 + 3] = fv.w;
    }
    // row stats (direct tile)
    {
        double rs_ = 0.0, ps_ = 0.0;
        float pc_ = 0.0f, nc_ = 0.0f;
#pragma unroll
        for (int i = 0; i < 16; i++) {
            float v = vals[i];
            rs_ += (double)v;
            if (v > 0.0f) { ps_ += (double)v; pc_ += 1.0f; }
            else if (v < 0.0f) { nc_ += 1.0f; }
        }
        rs_ += __shfl_xor(rs_, 1); rs_ += __shfl_xor(rs_, 2);
        ps_ += __shfl_xor(ps_, 1); ps_ += __shfl_xor(ps_, 2);
        pc_ += __shfl_xor(pc_, 1); pc_ += __shfl_xor(pc_, 2);
        nc_ += __shfl_xor(nc_, 1); nc_ += __shfl_xor(nc_, 2);
        if (cseg == 0) {
            int gr = row0 + r;
            atomicAdd(&rowsum[gr], rs_);
            atomicAdd(&possum[gr], ps_);
            atomicAdd(&pcnt[gr], (double)pc_ * PACK + (double)nc_);
        }
    }
    // direct store
    {
        size_t ob = (((size_t)(row0 + r)) << 13) + col0 + cseg * 16;
        if (f) {
            float* O = (float*)outv;
#pragma unroll
            for (int i4 = 0; i4 < 4; i4++)
                *(float4*)(O + ob + i4 * 4) =
                    make_float4(vals[i4 * 4], vals[i4 * 4 + 1], vals[i4 * 4 + 2], vals[i4 * 4 + 3]);
        } else {
            union { uint4 u; ushort16 s[8]; } p0, p1;
#pragma unroll
            for (int i = 0; i < 8; i++) p0.s[i] = f2bf(vals[i]);
#pragma unroll
            for (int i = 0; i < 8; i++) p1.s[i] = f2bf(vals[8 + i]);
            *(uint4*)((__hip_bfloat16*)outv + ob) = p0.u;
            *(uint4*)((__hip_bfloat16*)outv + ob + 8) = p1.u;
        }
    }
    // mirror store + column stats (off-diagonal only)
    if (bx != by) {
        float vm[16];
#pragma unroll
        for (int i = 0; i < 16; i++) vm[i] = Wf[(cseg * 16 + i) * 68 + r];
        double cs = 0.0, cp = 0.0;
        float cc = 0.0f, cn = 0.0f;
#pragma unroll
        for (int i = 0; i < 16; i++) {
            float v = vm[i];
            cs += (double)v;
            if (v > 0.0f) { cp += (double)v; cc += 1.0f; }
            else if (v < 0.0f) { cn += 1.0f; }
        }
        cs += __shfl_xor(cs, 1); cs += __shfl_xor(cs, 2);
        cp += __shfl_xor(cp, 1); cp += __shfl_xor(cp, 2);
        cc += __shfl_xor(cc, 1); cc += __shfl_xor(cc, 2);
        cn += __shfl_xor(cn, 1); cn += __shfl_xor(cn, 2);
        if (cseg == 0) {
            int gc = col0 + r;
            atomicAdd(&rowsum[gc], cs);
            atomicAdd(&possum[gc], cp);
            atomicAdd(&pcnt[gc], (double)cc * PACK + (double)cn);
        }
        size_t obm = (((size_t)(col0 + r)) << 13) + row0 + cseg * 16;
        if (f) {
            float* O = (float*)outv;
#pragma unroll
            for (int i4 = 0; i4 < 4; i4++)
                *(float4*)(O + obm + i4 * 4) =
                    make_float4(vm[i4 * 4], vm[i4 * 4 + 1], vm[i4 * 4 + 2], vm[i4 * 4 + 3]);
        } else {
            union { uint4 u; ushort16 s[8]; } m0, m1;
#pragma unroll
            for (int i = 0; i < 8; i++) m0.s[i] = f2bf(vm[i]);
#pragma unroll
            for (int i = 0; i < 8; i++) m1.s[i] = f2bf(vm[8 + i]);
            *(uint4*)((__hip_bfloat16*)outv + obm) = m0.u;
            *(uint4*)((__hip_bfloat16*)outv + obm + 8) = m1.u;
        }
    }
}

// ---------------- K3: per-row finalize + global positive stats ----------------
__global__ void rowfin_kernel(const double* __restrict__ rowsum, const double* __restrict__ possum,
                              const double* __restrict__ pcnt,
                              float* __restrict__ inv_rs, double* __restrict__ gstats) {
    __shared__ double sc[256], sn[256];
    int n = blockIdx.x * 256 + threadIdx.x;
    double rsumv = rowsum[n];
    double rs = rsumv + 1e-10;
    inv_rs[n] = (float)(1.0 / rs);
    double packed = pcnt[n];
    double pc = floor(packed * (1.0 / PACK));
    double nc = packed - pc * PACK;
    double contrib, cnt;
    if (rs > 0.0) { contrib = possum[n] / rs; cnt = pc; }
    else          { contrib = (rsumv - possum[n]) / rs; cnt = nc; }
    sc[threadIdx.x] = contrib; sn[threadIdx.x] = cnt;
    __syncthreads();
    for (int s = 128; s > 0; s >>= 1) {
        if (threadIdx.x < s) { sc[threadIdx.x] += sc[threadIdx.x + s]; sn[threadIdx.x] += sn[threadIdx.x + s]; }
        __syncthreads();
    }
    if (threadIdx.x == 0) { atomicAdd(&gstats[0], sc[0]); atomicAdd(&gstats[1], sn[0]); }
}

// ---------------- K3b: tau ----------------
__global__ void tau_kernel(const double* __restrict__ gstats, float* __restrict__ tau) {
    double cnt = gstats[1];
    if (cnt < 1.0) cnt = 1.0;
    double mp = gstats[0] / cnt;
    tau[0] = (mp > 0.0) ? (float)mp : 1.0f;   // TAU_FACTOR = 1.0
}

// ---------------- K4: R' = R*inv_rs, threshold, in-place on d_out ----------------
__global__ void thresh_kernel(void* __restrict__ R_,
                              const float* __restrict__ inv_rs,
                              const float* __restrict__ tau_p,
                              const int* __restrict__ flag) {
    int f = *flag;
    float tau = *tau_p;
    size_t base = ((size_t)blockIdx.x * 256 + threadIdx.x) * 8;
    if (base >= (size_t)NN * NN) return;
    float inv = inv_rs[base >> 13];
    if (f) {
        float* R = (float*)R_;
        float4 v0 = *(float4*)(R + base);
        float4 v1 = *(float4*)(R + base + 4);
        float vv[8] = {v0.x, v0.y, v0.z, v0.w, v1.x, v1.y, v1.z, v1.w};
#pragma unroll
        for (int t = 0; t < 8; t++) {
            float val = vv[t] * inv;
            vv[t] = (val >= tau) ? val : 0.0f;
        }
        *(float4*)(R + base)     = make_float4(vv[0], vv[1], vv[2], vv[3]);
        *(float4*)(R + base + 4) = make_float4(vv[4], vv[5], vv[6], vv[7]);
    } else {
        __hip_bfloat16* R = (__hip_bfloat16*)R_;
        union { uint4 u; ushort16 s[8]; } in, out;
        in.u = *(const uint4*)(R + base);
#pragma unroll
        for (int t = 0; t < 8; t++) {
            float val = bf2f(in.s[t]) * inv;
            float r = (val >= tau) ? val : 0.0f;
            out.s[t] = f2bf(r);
        }
        *(uint4*)(R + base) = out.u;
    }
}

// ---------------- sentinel: ws too small -> unmistakable absmax signature ----------------
__global__ void sentinel_kernel(uint32* __restrict__ out, size_t n32) {
    size_t i = (size_t)blockIdx.x * 256 + threadIdx.x;
    if (i < n32) out[i] = 0x47C35000u;
}

extern "C" void kernel_launch(void* const* d_in, const int* in_sizes, int n_in,
                              void* d_out, int out_size, void* d_ws, size_t ws_size,
                              hipStream_t stream) {
    const void* P = d_in[0];
    const void* A = d_in[1];

    char* ws = (char*)d_ws;
    size_t off = 0;
    ushort16* Xh = (ushort16*)(ws + off);   off += (size_t)NN * KD * 2;   // 8 MB
    ushort16* Xl = (ushort16*)(ws + off);   off += (size_t)NN * KD * 2;   // 8 MB
    ushort16* Xl2 = (ushort16*)(ws + off);  off += (size_t)NN * KD * 2;   // 8 MB
    float* sqv = (float*)(ws + off);        off += (size_t)NN * 4;
    double* rowsum = (double*)(ws + off);   off += (size_t)NN * 8;
    double* possum = (double*)(ws + off);   off += (size_t)NN * 8;
    double* pcnt = (double*)(ws + off);     off += (size_t)NN * 8;
    float* inv_rs = (float*)(ws + off);     off += (size_t)NN * 4;
    double* gstats = (double*)(ws + off);   off += 16;
    float* tau = (float*)(ws + off);        off += 16;
    int* flag = (int*)(ws + off);           off += 16;

    if (ws_size < off) {
        size_t n32 = ((size_t)out_size * 2) / 4;
        sentinel_kernel<<<(int)((n32 + 255) / 256), 256, 0, stream>>>((uint32*)d_out, n32);
        return;
    }

    detect_init_kernel<<<1 + (3 * NN + 255) / 256, 256, 0, stream>>>((const uint32*)A, flag, rowsum, gstats);
    prep_kernel<<<NN / 4, 256, 0, stream>>>(P, A, flag, Xh, Xl, Xl2, sqv);
    dim3 ggrid(128, 128);
    gemm_kernel<<<ggrid, 256, 0, stream>>>(Xh, Xl, Xl2, sqv, d_out, flag, rowsum, possum, pcnt);
    rowfin_kernel<<<NN / 256, 256, 0, stream>>>(rowsum, possum, pcnt, inv_rs, gstats);
    tau_kernel<<<1, 1, 0, stream>>>(gstats, tau);
    thresh_kernel<<<(int)(((size_t)NN * NN / 8 + 255) / 256), 256, 0, stream>>>(d_out, inv_rs, tau, flag);
}